// Round 2
// baseline (3090.591 us; speedup 1.0000x reference)
//
#include <hip/hip_runtime.h>

#define MUL0 32
#define MUL1 8
#define ND 56          // NODE_DIM
#define EF 64          // EDGE_FEAT
#define WN 1600        // WEIGHT_NUMEL
#define N_NODES 50000
#define N_EDGES 400000
#define ET 64          // edges per block
#define NCHUNK 13      // ceil(1600/128)

#define ALPHA 0.15811388300841897f   // 1/sqrt(32+8)
#define ISQ3  0.5773502691896258f    // 1/sqrt(3)

// LDS layout (float offsets), dynamic smem = 25856 floats = 103424 B:
//   sA   @ 0      [64][68]  edge_attr tile          (phase 1-2)
//   sW1  @ 4352   [64][68]  fc_w1                   (phase 1-2)
//   sW2c @ 0      [64][132] fc_w2 chunk             (chunk loop, overlays sA+sW1)
//   sHT  @ 8704   [64][68]  h transposed: sHT[c][e]
//   sX   @ 13056  [64][68]  x[0..55], sh[56..59], dotq[60..67]
//   sWo  @ 17408  [64][132] W chunk output
#define SMEM_BYTES 103424

__global__ __launch_bounds__(256, 1)
void tp_fused(const float* __restrict__ node_attr,
              const int* __restrict__ edge_index,
              const float* __restrict__ edge_attr,
              const float* __restrict__ edge_sh,
              const float* __restrict__ fc_w1,
              const float* __restrict__ fc_b1,
              const float* __restrict__ fc_w2,
              const float* __restrict__ fc_b2,
              float* __restrict__ seg,    // d_out as accumulator [N_NODES][56]
              float* __restrict__ cnt)    // d_ws [N_NODES]
{
    extern __shared__ float sm[];
    float* sA   = sm;            // [64][68]
    float* sW1  = sm + 4352;     // [64][68]
    float* sW2c = sm;            // [64][132]
    float* sHT  = sm + 8704;     // [64][68]
    float* sX   = sm + 13056;    // [64][68]
    float* sWo  = sm + 17408;    // [64][132]

    const int tid = threadIdx.x;
    const int e0 = blockIdx.x * ET;

    // ---- P1: stage edge_attr tile + fc_w1, gather node rows + sh ----
    #pragma unroll
    for (int r = 0; r < 4; ++r) {
        int idx = r * 256 + tid;          // 0..1023 float4 slots
        int row = idx >> 4, k4 = idx & 15;
        float4 va = *(const float4*)(edge_attr + (size_t)(e0 + row) * EF + k4 * 4);
        *(float4*)(sA + row * 68 + k4 * 4) = va;
        float4 vw = *(const float4*)(fc_w1 + (size_t)idx * 4);   // fc_w1[k][c] row-major
        *(float4*)(sW1 + row * 68 + k4 * 4) = vw;
    }
    {
        int e = tid >> 2, s = tid & 3;
        int dst = edge_index[N_EDGES + e0 + e];
        const float* xr = node_attr + (size_t)dst * ND;
        #pragma unroll
        for (int f = 0; f < 4; ++f) {
            int f4 = s + f * 4;           // 14 float4 per 56-float row
            if (f4 < 14)
                *(float4*)(sX + e * 68 + f4 * 4) = *(const float4*)(xr + f4 * 4);
        }
        if (s == 0)
            *(float4*)(sX + e * 68 + 56) = *(const float4*)(edge_sh + (size_t)(e0 + e) * 4);
    }
    __syncthreads();

    // ---- P2: FC1 (h = relu(ea @ w1 + b1)) -> sHT[c][e]; dotq -> sX[e][60..67] ----
    {
        int e = tid >> 2, s = tid & 3;
        int c0 = s * 16;
        float acc[16];
        #pragma unroll
        for (int i = 0; i < 16; ++i) acc[i] = fc_b1[c0 + i];
        #pragma unroll 4
        for (int k = 0; k < EF; ++k) {
            float a = sA[e * 68 + k];
            const float* wr = sW1 + k * 68 + c0;
            #pragma unroll
            for (int i = 0; i < 16; ++i) acc[i] = fmaf(a, wr[i], acc[i]);
        }
        #pragma unroll
        for (int i = 0; i < 16; ++i)
            sHT[(c0 + i) * 68 + e] = fmaxf(acc[i], 0.f);
        // dotq[u] = sum_j x1[u][j]*sh1[j], u = 2s, 2s+1
        #pragma unroll
        for (int q = 0; q < 2; ++q) {
            int u = s * 2 + q;
            float d = 0.f;
            #pragma unroll
            for (int j = 0; j < 3; ++j)
                d += sX[e * 68 + 32 + u * 3 + j] * sX[e * 68 + 57 + j];
            sX[e * 68 + 60 + u] = d;
        }
    }
    __syncthreads();

    // ---- chunk loop: W = h @ fc_w2 + b2 in 128-col chunks, consumed immediately ----
    const int ce = tid >> 2, cs = tid & 3;        // consumption: 4 threads/edge
    float o0a[8] = {0,0,0,0,0,0,0,0};             // w1-path  (w = cs + 4i)
    float o0b[8] = {0,0,0,0,0,0,0,0};             // w4-path
    float t2[2]  = {0,0};                          // w2-path  (w' = cs + 4q)
    float t3[2][3] = {{0,0,0},{0,0,0}};            // w3-path

    const int eb = tid >> 4, cb = tid & 15;        // GEMM mapping (tid < 128)
    const int e0g = eb * 8, c0g = cb * 8;

    for (int ch = 0; ch < NCHUNK; ++ch) {
        // stage fc_w2 chunk (zero-fill past 1600)
        #pragma unroll
        for (int r = 0; r < 8; ++r) {
            int idx = r * 256 + tid;               // 0..2047 float4 slots
            int row = idx >> 5, cc4 = idx & 31;
            int g = ch * 128 + cc4 * 4;
            float4 v = make_float4(0.f, 0.f, 0.f, 0.f);
            if (g < WN) v = *(const float4*)(fc_w2 + (size_t)row * WN + g);
            *(float4*)(sW2c + row * 132 + cc4 * 4) = v;
        }
        __syncthreads();

        if (tid < 128) {                           // 2 waves do the 64x64x128 GEMM, 8x8 tiles
            float acc[8][8];
            int g = ch * 128 + c0g;
            float4 b0 = make_float4(0,0,0,0), b1v = make_float4(0,0,0,0);
            if (g < WN) {
                b0  = *(const float4*)(fc_b2 + g);
                b1v = *(const float4*)(fc_b2 + g + 4);
            }
            float bb[8] = {b0.x,b0.y,b0.z,b0.w,b1v.x,b1v.y,b1v.z,b1v.w};
            #pragma unroll
            for (int i = 0; i < 8; ++i)
                #pragma unroll
                for (int j = 0; j < 8; ++j) acc[i][j] = bb[j];
            #pragma unroll 4
            for (int k = 0; k < 64; ++k) {
                float4 h0 = *(float4*)(sHT + k * 68 + e0g);
                float4 h1 = *(float4*)(sHT + k * 68 + e0g + 4);
                float4 w0 = *(float4*)(sW2c + k * 132 + c0g);
                float4 w1v = *(float4*)(sW2c + k * 132 + c0g + 4);
                float he[8] = {h0.x,h0.y,h0.z,h0.w,h1.x,h1.y,h1.z,h1.w};
                float wc[8] = {w0.x,w0.y,w0.z,w0.w,w1v.x,w1v.y,w1v.z,w1v.w};
                #pragma unroll
                for (int i = 0; i < 8; ++i)
                    #pragma unroll
                    for (int j = 0; j < 8; ++j)
                        acc[i][j] = fmaf(he[i], wc[j], acc[i][j]);
            }
            #pragma unroll
            for (int i = 0; i < 8; ++i) {
                *(float4*)(sWo + (e0g + i) * 132 + c0g)     = make_float4(acc[i][0],acc[i][1],acc[i][2],acc[i][3]);
                *(float4*)(sWo + (e0g + i) * 132 + c0g + 4) = make_float4(acc[i][4],acc[i][5],acc[i][6],acc[i][7]);
            }
        }
        __syncthreads();

        // consume this chunk into TP accumulators
        const float* We = sWo + ce * 132;
        const float* Xe = sX + ce * 68;
        if (ch < 8) {                               // w1: u = ch*4 .. +4, col = (u-u0)*32 + w
            int u0 = ch * 4;
            #pragma unroll
            for (int uu = 0; uu < 4; ++uu) {
                float xv = Xe[u0 + uu];
                #pragma unroll
                for (int i = 0; i < 8; ++i)
                    o0a[i] = fmaf(xv, We[uu * 32 + cs + 4 * i], o0a[i]);
            }
        } else if (ch < 10) {                       // w2: u = (ch-8)*16 .. +16, col = uu*8 + w'
            int ub = (ch - 8) * 16;
            #pragma unroll
            for (int uu = 0; uu < 16; ++uu) {
                float xv = Xe[ub + uu];
                #pragma unroll
                for (int q = 0; q < 2; ++q)
                    t2[q] = fmaf(xv, We[uu * 8 + cs + 4 * q], t2[q]);
            }
        } else if (ch == 10) {                      // w3 (cols 0..63) + w4 u=0,1 (cols 64..127)
            #pragma unroll
            for (int u = 0; u < 8; ++u) {
                #pragma unroll
                for (int q = 0; q < 2; ++q) {
                    float wv = We[u * 8 + cs + 4 * q];
                    #pragma unroll
                    for (int j = 0; j < 3; ++j)
                        t3[q][j] = fmaf(Xe[32 + u * 3 + j], wv, t3[q][j]);
                }
            }
            #pragma unroll
            for (int u = 0; u < 2; ++u) {
                float dq = Xe[60 + u];
                #pragma unroll
                for (int i = 0; i < 8; ++i)
                    o0b[i] = fmaf(dq, We[64 + u * 32 + cs + 4 * i], o0b[i]);
            }
        } else if (ch == 11) {                      // w4 u=2..5
            #pragma unroll
            for (int uu = 0; uu < 4; ++uu) {
                float dq = Xe[62 + uu];
                #pragma unroll
                for (int i = 0; i < 8; ++i)
                    o0b[i] = fmaf(dq, We[uu * 32 + cs + 4 * i], o0b[i]);
            }
        } else {                                    // ch == 12: w4 u=6,7 (cols 0..63 valid)
            #pragma unroll
            for (int uu = 0; uu < 2; ++uu) {
                float dq = Xe[66 + uu];
                #pragma unroll
                for (int i = 0; i < 8; ++i)
                    o0b[i] = fmaf(dq, We[uu * 32 + cs + 4 * i], o0b[i]);
            }
        }
    }

    // ---- scatter: out0[w]=(sh0*o0a + isq3*o0b)*alpha; out1[w'][j]=(t2*sh1[j]+sh0*t3)*alpha ----
    {
        int src = edge_index[e0 + ce];
        float sh0 = sX[ce * 68 + 56];
        float* segr = seg + (size_t)src * ND;
        #pragma unroll
        for (int i = 0; i < 8; ++i) {
            float v = (sh0 * o0a[i] + ISQ3 * o0b[i]) * ALPHA;
            atomicAdd(segr + cs + 4 * i, v);
        }
        #pragma unroll
        for (int q = 0; q < 2; ++q) {
            int wp = cs + 4 * q;
            #pragma unroll
            for (int j = 0; j < 3; ++j) {
                float v = (t2[q] * sX[ce * 68 + 57 + j] + sh0 * t3[q][j]) * ALPHA;
                atomicAdd(segr + 32 + wp * 3 + j, v);
            }
        }
        if (cs == 0) atomicAdd(cnt + src, 1.0f);
    }
}

__global__ __launch_bounds__(256)
void tp_finalize(const float* __restrict__ node_attr,
                 const float* __restrict__ cnt,
                 float* __restrict__ out, int totalf4)
{
    int idx = blockIdx.x * 256 + threadIdx.x;
    if (idx >= totalf4) return;
    int n = idx / 14;                              // 14 float4 per 56-float row
    float inv = 1.f / fmaxf(cnt[n], 1.f);
    float4 s = *(float4*)(out + (size_t)idx * 4);
    const float4 a = *(const float4*)(node_attr + (size_t)idx * 4);
    s.x = fmaf(s.x, inv, a.x);
    s.y = fmaf(s.y, inv, a.y);
    s.z = fmaf(s.z, inv, a.z);
    s.w = fmaf(s.w, inv, a.w);
    *(float4*)(out + (size_t)idx * 4) = s;
}

extern "C" void kernel_launch(void* const* d_in, const int* in_sizes, int n_in,
                              void* d_out, int out_size, void* d_ws, size_t ws_size,
                              hipStream_t stream)
{
    const float* node_attr = (const float*)d_in[0];
    const int*   edge_index= (const int*)d_in[1];
    const float* edge_attr = (const float*)d_in[2];
    const float* edge_sh   = (const float*)d_in[3];
    const float* fc_w1     = (const float*)d_in[4];
    const float* fc_b1     = (const float*)d_in[5];
    const float* fc_w2     = (const float*)d_in[6];
    const float* fc_b2     = (const float*)d_in[7];
    float* seg = (float*)d_out;
    float* cnt = (float*)d_ws;

    hipFuncSetAttribute((const void*)tp_fused,
                        hipFuncAttributeMaxDynamicSharedMemorySize, SMEM_BYTES);

    hipMemsetAsync(d_out, 0, (size_t)out_size * sizeof(float), stream);
    hipMemsetAsync(d_ws, 0, (size_t)N_NODES * sizeof(float), stream);

    tp_fused<<<N_EDGES / ET, 256, SMEM_BYTES, stream>>>(
        node_attr, edge_index, edge_attr, edge_sh,
        fc_w1, fc_b1, fc_w2, fc_b2, seg, cnt);

    int totalf4 = N_NODES * (ND / 4);              // 700000
    tp_finalize<<<(totalf4 + 255) / 256, 256, 0, stream>>>(node_attr, cnt, seg, totalf4);
}

// Round 3
// 984.583 us; speedup vs baseline: 3.1390x; 3.1390x over previous
//
#include <hip/hip_runtime.h>

#define ND 56
#define EF 64
#define WN 1600
#define N_NODES 50000
#define N_EDGES 400000
#define EB 128

#define ALPHA 0.15811388300841897f   // 1/sqrt(32+8)
#define ISQ3  0.5773502691896258f    // 1/sqrt(3)

typedef __attribute__((ext_vector_type(8))) short bfrag;   // 8 bf16 = 4 VGPR
typedef __attribute__((ext_vector_type(4))) float vf4;

__device__ __align__(16) unsigned short g_w2t[WN * EF];    // fc_w2^T bf16 [w][c]

static __device__ __forceinline__ unsigned short f2bf(float x) {
    union { float f; unsigned int u; } a; a.f = x;
    unsigned int r = a.u + 0x7fffu + ((a.u >> 16) & 1u);   // RNE
    return (unsigned short)(r >> 16);
}

__global__ void w2t_conv(const float* __restrict__ fc_w2) {
    int c = blockIdx.x;                                    // 0..63
    for (int w = threadIdx.x; w < WN; w += 256)
        g_w2t[w * EF + c] = f2bf(fc_w2[(size_t)c * WN + w]);
}

static __device__ __forceinline__ vf4 mm2(bfrag a0, bfrag a1, bfrag b0, bfrag b1) {
    vf4 d = {0.f, 0.f, 0.f, 0.f};
    d = __builtin_amdgcn_mfma_f32_16x16x32_bf16(a0, b0, d, 0, 0, 0);
    d = __builtin_amdgcn_mfma_f32_16x16x32_bf16(a1, b1, d, 0, 0, 0);
    return d;
}

// LDS: sAX f32[128][68] @0 (34816B) — edge_attr tile during FC1, then x/sh/dot.
//      sW1 f32[64][68] @f8704 (17408B) — fc_w1, dead after FC1 compute.
//      sHb u16[128][72] @f8704 (18432B) — h bf16, OVERLAYS sW1 (written from regs
//      after barrier). Peak 53248B -> 3 blocks/CU.
__global__ __launch_bounds__(256, 3)
void tp_fused(const float* __restrict__ node_attr,
              const int* __restrict__ edge_index,
              const float* __restrict__ edge_attr,
              const float* __restrict__ edge_sh,
              const float* __restrict__ fc_w1,
              const float* __restrict__ fc_b1,
              const float* __restrict__ fc_b2,
              float* __restrict__ seg,
              float* __restrict__ cnt)
{
    __shared__ float sm[13312];                  // 53248 B
    float* sAX = sm;                             // [128][68]
    float* sW1 = sm + 8704;                      // [64][68]
    unsigned short* sHb = (unsigned short*)(sm + 8704);  // [128][72]

    const int tid = threadIdx.x;
    const int e0 = blockIdx.x * EB;

    // ---- P1: stage edge_attr + fc_w1 ----
    #pragma unroll
    for (int r = 0; r < 8; ++r) {
        int idx = r * 256 + tid;                 // 2048 float4
        int row = idx >> 4, k4 = idx & 15;
        *(float4*)(sAX + row * 68 + k4 * 4) =
            *(const float4*)(edge_attr + (size_t)(e0 + row) * EF + k4 * 4);
    }
    #pragma unroll
    for (int r = 0; r < 4; ++r) {
        int idx = r * 256 + tid;                 // 1024 float4
        int row = idx >> 4, k4 = idx & 15;
        *(float4*)(sW1 + row * 68 + k4 * 4) = *(const float4*)(fc_w1 + (size_t)idx * 4);
    }
    __syncthreads();

    // ---- P2: FC1 fp32, h kept in regs ----
    const int er0 = (tid & 31) * 4, cc0 = (tid >> 5) * 8;
    float hacc[4][8];
    {
        #pragma unroll
        for (int j = 0; j < 8; ++j) {
            float b = fc_b1[cc0 + j];
            hacc[0][j] = b; hacc[1][j] = b; hacc[2][j] = b; hacc[3][j] = b;
        }
        #pragma unroll 4
        for (int k = 0; k < EF; ++k) {
            float a0 = sAX[(er0 + 0) * 68 + k], a1 = sAX[(er0 + 1) * 68 + k];
            float a2 = sAX[(er0 + 2) * 68 + k], a3 = sAX[(er0 + 3) * 68 + k];
            const float* wr = sW1 + k * 68 + cc0;
            #pragma unroll
            for (int j = 0; j < 8; ++j) {
                float w = wr[j];
                hacc[0][j] = fmaf(a0, w, hacc[0][j]);
                hacc[1][j] = fmaf(a1, w, hacc[1][j]);
                hacc[2][j] = fmaf(a2, w, hacc[2][j]);
                hacc[3][j] = fmaf(a3, w, hacc[3][j]);
            }
        }
    }
    __syncthreads();   // sAX & sW1 reads done

    // ---- P2b: h->bf16 into sHb (overlays sW1); gather x/sh/dot into sAX ----
    #pragma unroll
    for (int i = 0; i < 4; ++i)
        #pragma unroll
        for (int j = 0; j < 8; j += 2) {
            unsigned int pk = (unsigned int)f2bf(fmaxf(hacc[i][j], 0.f)) |
                              ((unsigned int)f2bf(fmaxf(hacc[i][j + 1], 0.f)) << 16);
            *(unsigned int*)(sHb + (er0 + i) * 72 + cc0 + j) = pk;
        }
    {
        int e = tid >> 1, hf = tid & 1;
        const int dst = edge_index[N_EDGES + e0 + e];
        const float* xr = node_attr + (size_t)dst * ND;
        float* Xe = sAX + e * 68;
        if (hf == 0) {
            #pragma unroll
            for (int f = 0; f < 8; ++f)
                *(float4*)(Xe + f * 4) = *(const float4*)(xr + f * 4);
        } else {
            float4 xv[6];
            #pragma unroll
            for (int f = 0; f < 6; ++f) {
                xv[f] = *(const float4*)(xr + 32 + f * 4);
                *(float4*)(Xe + 32 + f * 4) = xv[f];
            }
            float4 shv = *(const float4*)(edge_sh + (size_t)(e0 + e) * 4);
            *(float4*)(Xe + 56) = shv;
            #define X1F(i) ((i&3)==0 ? xv[(i)>>2].x : (i&3)==1 ? xv[(i)>>2].y : (i&3)==2 ? xv[(i)>>2].z : xv[(i)>>2].w)
            #pragma unroll
            for (int u = 0; u < 8; ++u)
                Xe[60 + u] = X1F(u*3+0) * shv.y + X1F(u*3+1) * shv.z + X1F(u*3+2) * shv.w;
            #undef X1F
        }
    }
    __syncthreads();

    // ---- P4: MFMA chunk loop, consume in registers ----
    const int lane = tid & 63, wv = tid >> 6;
    const int le = lane & 15, g = lane >> 4;
    const int eA = wv * 32 + le, eB = eA + 16;

    bfrag bA0 = *(const bfrag*)(sHb + eA * 72 + g * 8);
    bfrag bA1 = *(const bfrag*)(sHb + eA * 72 + 32 + g * 8);
    bfrag bB0 = *(const bfrag*)(sHb + eB * 72 + g * 8);
    bfrag bB1 = *(const bfrag*)(sHb + eB * 72 + 32 + g * 8);

    const float* XA = sAX + eA * 68;
    const float* XB = sAX + eB * 68;
    vf4 shA = *(const vf4*)(XA + 56);
    vf4 shB = *(const vf4*)(XB + 56);

    const unsigned short* Ab = g_w2t + le * EF + g * 8;
    const float* B2 = fc_b2 + g * 4;

    float o0aA[8] = {0,0,0,0,0,0,0,0}, o0aB[8] = {0,0,0,0,0,0,0,0};
    float o0bA[8] = {0,0,0,0,0,0,0,0}, o0bB[8] = {0,0,0,0,0,0,0,0};
    float o1A[4][3] = {{0,0,0},{0,0,0},{0,0,0},{0,0,0}};
    float o1B[4][3] = {{0,0,0},{0,0,0},{0,0,0},{0,0,0}};

    // w1: tiles 0..63 (rows u*32+w), u=t>>1, acc idx (t&1)*4+r
    #pragma unroll 2
    for (int t2 = 0; t2 < 32; ++t2) {
        const unsigned short* At = Ab + t2 * 2048;
        bfrag a00 = *(const bfrag*)(At);
        bfrag a01 = *(const bfrag*)(At + 32);
        bfrag a10 = *(const bfrag*)(At + 1024);
        bfrag a11 = *(const bfrag*)(At + 1056);
        vf4 b20 = *(const vf4*)(B2 + t2 * 32);
        vf4 b21 = *(const vf4*)(B2 + t2 * 32 + 16);
        float xuA = XA[t2], xuB = XB[t2];
        vf4 dA0 = mm2(a00, a01, bA0, bA1);
        vf4 dB0 = mm2(a00, a01, bB0, bB1);
        vf4 dA1 = mm2(a10, a11, bA0, bA1);
        vf4 dB1 = mm2(a10, a11, bB0, bB1);
        #pragma unroll
        for (int r = 0; r < 4; ++r) {
            o0aA[r]     = fmaf(xuA, dA0[r] + b20[r], o0aA[r]);
            o0aB[r]     = fmaf(xuB, dB0[r] + b20[r], o0aB[r]);
            o0aA[4 + r] = fmaf(xuA, dA1[r] + b21[r], o0aA[4 + r]);
            o0aB[4 + r] = fmaf(xuB, dB1[r] + b21[r], o0aB[4 + r]);
        }
    }

    // w2: tiles 64..79 (rows 1024+u*8+w'), u=2(t-64)+(g>>1), w'=(g&1)*4+r
    #pragma unroll 2
    for (int t = 64; t < 80; ++t) {
        const unsigned short* At = Ab + t * 1024;
        bfrag a0 = *(const bfrag*)(At);
        bfrag a1 = *(const bfrag*)(At + 32);
        vf4 b2v = *(const vf4*)(B2 + t * 16);
        int u = 2 * (t - 64) + (g >> 1);
        float xuA = XA[u], xuB = XB[u];
        float cA0 = xuA * shA[1], cA1 = xuA * shA[2], cA2 = xuA * shA[3];
        float cB0 = xuB * shB[1], cB1 = xuB * shB[2], cB2 = xuB * shB[3];
        vf4 dA = mm2(a0, a1, bA0, bA1);
        vf4 dB = mm2(a0, a1, bB0, bB1);
        #pragma unroll
        for (int r = 0; r < 4; ++r) {
            float WA = dA[r] + b2v[r], WB = dB[r] + b2v[r];
            o1A[r][0] = fmaf(cA0, WA, o1A[r][0]);
            o1A[r][1] = fmaf(cA1, WA, o1A[r][1]);
            o1A[r][2] = fmaf(cA2, WA, o1A[r][2]);
            o1B[r][0] = fmaf(cB0, WB, o1B[r][0]);
            o1B[r][1] = fmaf(cB1, WB, o1B[r][1]);
            o1B[r][2] = fmaf(cB2, WB, o1B[r][2]);
        }
    }

    // w3: tiles 80..83 (rows 1280+u*8+w'), u=2(t-80)+(g>>1)
    #pragma unroll
    for (int t = 80; t < 84; ++t) {
        const unsigned short* At = Ab + t * 1024;
        bfrag a0 = *(const bfrag*)(At);
        bfrag a1 = *(const bfrag*)(At + 32);
        vf4 b2v = *(const vf4*)(B2 + t * 16);
        int u = 2 * (t - 80) + (g >> 1);
        float cA0 = shA[0] * XA[32 + u * 3 + 0];
        float cA1 = shA[0] * XA[32 + u * 3 + 1];
        float cA2 = shA[0] * XA[32 + u * 3 + 2];
        float cB0 = shB[0] * XB[32 + u * 3 + 0];
        float cB1 = shB[0] * XB[32 + u * 3 + 1];
        float cB2 = shB[0] * XB[32 + u * 3 + 2];
        vf4 dA = mm2(a0, a1, bA0, bA1);
        vf4 dB = mm2(a0, a1, bB0, bB1);
        #pragma unroll
        for (int r = 0; r < 4; ++r) {
            float WA = dA[r] + b2v[r], WB = dB[r] + b2v[r];
            o1A[r][0] = fmaf(cA0, WA, o1A[r][0]);
            o1A[r][1] = fmaf(cA1, WA, o1A[r][1]);
            o1A[r][2] = fmaf(cA2, WA, o1A[r][2]);
            o1B[r][0] = fmaf(cB0, WB, o1B[r][0]);
            o1B[r][1] = fmaf(cB1, WB, o1B[r][1]);
            o1B[r][2] = fmaf(cB2, WB, o1B[r][2]);
        }
    }

    // w4: tiles 84..99 (rows 1344+u*32+w), u=(t-84)>>1
    #pragma unroll 2
    for (int t2 = 0; t2 < 8; ++t2) {
        const unsigned short* At = Ab + (84 + 2 * t2) * 1024;
        bfrag a00 = *(const bfrag*)(At);
        bfrag a01 = *(const bfrag*)(At + 32);
        bfrag a10 = *(const bfrag*)(At + 1024);
        bfrag a11 = *(const bfrag*)(At + 1056);
        vf4 b20 = *(const vf4*)(B2 + (84 + 2 * t2) * 16);
        vf4 b21 = *(const vf4*)(B2 + (84 + 2 * t2) * 16 + 16);
        float dqA = XA[60 + t2], dqB = XB[60 + t2];
        vf4 dA0 = mm2(a00, a01, bA0, bA1);
        vf4 dB0 = mm2(a00, a01, bB0, bB1);
        vf4 dA1 = mm2(a10, a11, bA0, bA1);
        vf4 dB1 = mm2(a10, a11, bB0, bB1);
        #pragma unroll
        for (int r = 0; r < 4; ++r) {
            o0bA[r]     = fmaf(dqA, dA0[r] + b20[r], o0bA[r]);
            o0bB[r]     = fmaf(dqB, dB0[r] + b20[r], o0bB[r]);
            o0bA[4 + r] = fmaf(dqA, dA1[r] + b21[r], o0bA[4 + r]);
            o0bB[4 + r] = fmaf(dqB, dB1[r] + b21[r], o0bB[4 + r]);
        }
    }

    // ---- scatter ----
    const int srcA = edge_index[e0 + eA];
    const int srcB = edge_index[e0 + eB];
    float* segA = seg + (size_t)srcA * ND;
    float* segB = seg + (size_t)srcB * ND;
    #pragma unroll
    for (int j = 0; j < 8; ++j) {
        int w = (j >> 2) * 16 + g * 4 + (j & 3);
        atomicAdd(segA + w, (shA[0] * o0aA[j] + ISQ3 * o0bA[j]) * ALPHA);
        atomicAdd(segB + w, (shB[0] * o0aB[j] + ISQ3 * o0bB[j]) * ALPHA);
    }
    #pragma unroll
    for (int r = 0; r < 4; ++r)
        #pragma unroll
        for (int j = 0; j < 3; ++j) {
            o1A[r][j] += __shfl_xor(o1A[r][j], 32);
            o1B[r][j] += __shfl_xor(o1B[r][j], 32);
        }
    if (lane < 32) {
        #pragma unroll
        for (int r = 0; r < 4; ++r) {
            int wp = g * 4 + r;   // g in {0,1}
            #pragma unroll
            for (int j = 0; j < 3; ++j) {
                atomicAdd(segA + 32 + wp * 3 + j, o1A[r][j] * ALPHA);
                atomicAdd(segB + 32 + wp * 3 + j, o1B[r][j] * ALPHA);
            }
        }
    }
    if (g == 0) { atomicAdd(cnt + srcA, 1.f); atomicAdd(cnt + srcB, 1.f); }
}

__global__ __launch_bounds__(256)
void tp_finalize(const float* __restrict__ node_attr,
                 const float* __restrict__ cnt,
                 float* __restrict__ out, int totalf4)
{
    int idx = blockIdx.x * 256 + threadIdx.x;
    if (idx >= totalf4) return;
    int n = idx / 14;
    float inv = 1.f / fmaxf(cnt[n], 1.f);
    float4 s = *(float4*)(out + (size_t)idx * 4);
    const float4 a = *(const float4*)(node_attr + (size_t)idx * 4);
    s.x = fmaf(s.x, inv, a.x);
    s.y = fmaf(s.y, inv, a.y);
    s.z = fmaf(s.z, inv, a.z);
    s.w = fmaf(s.w, inv, a.w);
    *(float4*)(out + (size_t)idx * 4) = s;
}

extern "C" void kernel_launch(void* const* d_in, const int* in_sizes, int n_in,
                              void* d_out, int out_size, void* d_ws, size_t ws_size,
                              hipStream_t stream)
{
    const float* node_attr  = (const float*)d_in[0];
    const int*   edge_index = (const int*)d_in[1];
    const float* edge_attr  = (const float*)d_in[2];
    const float* edge_sh    = (const float*)d_in[3];
    const float* fc_w1      = (const float*)d_in[4];
    const float* fc_b1      = (const float*)d_in[5];
    const float* fc_w2      = (const float*)d_in[6];
    const float* fc_b2      = (const float*)d_in[7];
    float* seg = (float*)d_out;
    float* cnt = (float*)d_ws;

    hipMemsetAsync(d_out, 0, (size_t)out_size * sizeof(float), stream);
    hipMemsetAsync(d_ws, 0, (size_t)N_NODES * sizeof(float), stream);

    w2t_conv<<<EF, 256, 0, stream>>>(fc_w2);

    tp_fused<<<N_EDGES / EB, 256, 0, stream>>>(
        node_attr, edge_index, edge_attr, edge_sh,
        fc_w1, fc_b1, fc_b2, seg, cnt);

    int totalf4 = N_NODES * (ND / 4);
    tp_finalize<<<(totalf4 + 255) / 256, 256, 0, stream>>>(node_attr, cnt, seg, totalf4);
}

// Round 7
// 613.370 us; speedup vs baseline: 5.0387x; 1.6052x over previous
//
#include <hip/hip_runtime.h>

#define ND 56
#define EF 64
#define WN 1600
#define N_NODES 50000
#define N_EDGES 400000
#define EB 128
#define NB_SCAN 196            // ceil(50000/256)

#define ALPHA 0.15811388300841897f   // 1/sqrt(32+8)
#define ISQ3  0.5773502691896258f    // 1/sqrt(3)

typedef __attribute__((ext_vector_type(8))) short bfrag;   // 8 bf16 = 4 VGPR
typedef __attribute__((ext_vector_type(4))) float vf4;

__device__ __align__(16) unsigned short g_w2t[WN * EF];    // fc_w2^T bf16 [w][c]

static __device__ __forceinline__ unsigned short f2bf(float x) {
    union { float f; unsigned int u; } a; a.f = x;
    unsigned int r = a.u + 0x7fffu + ((a.u >> 16) & 1u);   // RNE
    return (unsigned short)(r >> 16);
}

__global__ void w2t_conv(const float* __restrict__ fc_w2) {
    int c = blockIdx.x;                                    // 0..63
    for (int w = threadIdx.x; w < WN; w += 256)
        g_w2t[w * EF + c] = f2bf(fc_w2[(size_t)c * WN + w]);
}

static __device__ __forceinline__ vf4 mm2(bfrag a0, bfrag a1, bfrag b0, bfrag b1) {
    vf4 d = {0.f, 0.f, 0.f, 0.f};
    d = __builtin_amdgcn_mfma_f32_16x16x32_bf16(a0, b0, d, 0, 0, 0);
    d = __builtin_amdgcn_mfma_f32_16x16x32_bf16(a1, b1, d, 0, 0, 0);
    return d;
}

// ---------------- CSR build kernels ----------------
__global__ void k_hist(const int* __restrict__ ei, int* __restrict__ hist) {
    int e = blockIdx.x * 256 + threadIdx.x;
    if (e < N_EDGES) atomicAdd(&hist[ei[e]], 1);
}

__global__ void k_scan1(const int* __restrict__ hist, int* __restrict__ bsum) {
    __shared__ int s[256];
    int t = threadIdx.x, i = blockIdx.x * 256 + t;
    s[t] = (i < N_NODES) ? hist[i] : 0;
    __syncthreads();
    for (int st = 128; st > 0; st >>= 1) {
        if (t < st) s[t] += s[t + st];
        __syncthreads();
    }
    if (t == 0) bsum[blockIdx.x] = s[0];
}

__global__ void k_scan2(const int* __restrict__ bsum, int* __restrict__ bbase) {
    __shared__ int s[256];
    int t = threadIdx.x;
    int v = (t < NB_SCAN) ? bsum[t] : 0;
    s[t] = v;
    __syncthreads();
    for (int st = 1; st < 256; st <<= 1) {
        int x = s[t];
        if (t >= st) x += s[t - st];
        __syncthreads();
        s[t] = x;
        __syncthreads();
    }
    if (t < NB_SCAN) bbase[t] = s[t] - v;           // exclusive
}

__global__ void k_scan3(const int* __restrict__ hist, const int* __restrict__ bbase,
                        int* __restrict__ cursor) {
    __shared__ int s[256];
    int t = threadIdx.x, i = blockIdx.x * 256 + t;
    int v = (i < N_NODES) ? hist[i] : 0;
    s[t] = v;
    __syncthreads();
    for (int st = 1; st < 256; st <<= 1) {
        int x = s[t];
        if (t >= st) x += s[t - st];
        __syncthreads();
        s[t] = x;
        __syncthreads();
    }
    if (i < N_NODES) cursor[i] = bbase[blockIdx.x] + s[t] - v;   // exclusive
}

__global__ void k_scatter(const int* __restrict__ ei, int* __restrict__ cursor,
                          int* __restrict__ perm) {
    int e = blockIdx.x * 256 + threadIdx.x;
    if (e >= N_EDGES) return;
    int pos = atomicAdd(&cursor[ei[e]], 1);
    perm[pos] = e;
}

// ---------------- main fused kernel ----------------
// LDS: sAX f32[128][68] @0 — edge_attr tile during FC1, then x/sh/dot, then
//      sTP f32[128][60] (aggregation) overlays it.
//      sW1 f32[64][68] @f8704 — fc_w1, dead after FC1; sHb u16[128][72] overlays;
//      sSrc/sIsHd/sEnd (384 ints) overlay during aggregation.
__global__ __launch_bounds__(256, 3)
void tp_fused(const float* __restrict__ node_attr,
              const int* __restrict__ edge_index,
              const float* __restrict__ edge_attr,
              const float* __restrict__ edge_sh,
              const float* __restrict__ fc_w1,
              const float* __restrict__ fc_b1,
              const float* __restrict__ fc_b2,
              float* __restrict__ seg,
              const int* __restrict__ perm)
{
    __shared__ float sm[13312];                  // 53248 B
    float* sAX = sm;                             // [128][68]
    float* sW1 = sm + 8704;                      // [64][68]
    unsigned short* sHb = (unsigned short*)(sm + 8704);  // [128][72]

    const int tid = threadIdx.x;
    const int e0 = blockIdx.x * EB;

    // ---- P1: stage edge_attr (perm-gathered) + fc_w1 ----
    #pragma unroll
    for (int r = 0; r < 8; ++r) {
        int idx = r * 256 + tid;                 // 2048 float4
        int row = idx >> 4, k4 = idx & 15;
        int ep = perm[e0 + row];
        *(float4*)(sAX + row * 68 + k4 * 4) =
            *(const float4*)(edge_attr + (size_t)ep * EF + k4 * 4);
    }
    #pragma unroll
    for (int r = 0; r < 4; ++r) {
        int idx = r * 256 + tid;                 // 1024 float4
        int row = idx >> 4, k4 = idx & 15;
        *(float4*)(sW1 + row * 68 + k4 * 4) = *(const float4*)(fc_w1 + (size_t)idx * 4);
    }
    __syncthreads();

    // ---- P2: FC1 fp32 ----
    const int er0 = (tid & 31) * 4, cc0 = (tid >> 5) * 8;
    float hacc[4][8];
    {
        #pragma unroll
        for (int j = 0; j < 8; ++j) {
            float b = fc_b1[cc0 + j];
            hacc[0][j] = b; hacc[1][j] = b; hacc[2][j] = b; hacc[3][j] = b;
        }
        #pragma unroll 4
        for (int k = 0; k < EF; ++k) {
            float a0 = sAX[(er0 + 0) * 68 + k], a1 = sAX[(er0 + 1) * 68 + k];
            float a2 = sAX[(er0 + 2) * 68 + k], a3 = sAX[(er0 + 3) * 68 + k];
            const float* wr = sW1 + k * 68 + cc0;
            #pragma unroll
            for (int j = 0; j < 8; ++j) {
                float w = wr[j];
                hacc[0][j] = fmaf(a0, w, hacc[0][j]);
                hacc[1][j] = fmaf(a1, w, hacc[1][j]);
                hacc[2][j] = fmaf(a2, w, hacc[2][j]);
                hacc[3][j] = fmaf(a3, w, hacc[3][j]);
            }
        }
    }
    __syncthreads();   // sAX & sW1 reads done

    // ---- P2b: h->bf16 into sHb; gather x/sh/dot into sAX ----
    #pragma unroll
    for (int i = 0; i < 4; ++i)
        #pragma unroll
        for (int j = 0; j < 8; j += 2) {
            unsigned int pk = (unsigned int)f2bf(fmaxf(hacc[i][j], 0.f)) |
                              ((unsigned int)f2bf(fmaxf(hacc[i][j + 1], 0.f)) << 16);
            *(unsigned int*)(sHb + (er0 + i) * 72 + cc0 + j) = pk;
        }
    {
        int e = tid >> 1, hf = tid & 1;
        int ep = perm[e0 + e];
        const int dst = edge_index[N_EDGES + ep];
        const float* xr = node_attr + (size_t)dst * ND;
        float* Xe = sAX + e * 68;
        if (hf == 0) {
            #pragma unroll
            for (int f = 0; f < 8; ++f)
                *(float4*)(Xe + f * 4) = *(const float4*)(xr + f * 4);
        } else {
            float4 xv[6];
            #pragma unroll
            for (int f = 0; f < 6; ++f) {
                xv[f] = *(const float4*)(xr + 32 + f * 4);
                *(float4*)(Xe + 32 + f * 4) = xv[f];
            }
            float4 shv = *(const float4*)(edge_sh + (size_t)ep * 4);
            *(float4*)(Xe + 56) = shv;
            #define X1F(i) ((i&3)==0 ? xv[(i)>>2].x : (i&3)==1 ? xv[(i)>>2].y : (i&3)==2 ? xv[(i)>>2].z : xv[(i)>>2].w)
            #pragma unroll
            for (int u = 0; u < 8; ++u)
                Xe[60 + u] = X1F(u*3+0) * shv.y + X1F(u*3+1) * shv.z + X1F(u*3+2) * shv.w;
            #undef X1F
        }
    }
    __syncthreads();

    // ---- P4: MFMA chunk loop, consume in registers ----
    const int lane = tid & 63, wv = tid >> 6;
    const int le = lane & 15, g = lane >> 4;
    const int eA = wv * 32 + le, eB = eA + 16;

    bfrag bA0 = *(const bfrag*)(sHb + eA * 72 + g * 8);
    bfrag bA1 = *(const bfrag*)(sHb + eA * 72 + 32 + g * 8);
    bfrag bB0 = *(const bfrag*)(sHb + eB * 72 + g * 8);
    bfrag bB1 = *(const bfrag*)(sHb + eB * 72 + 32 + g * 8);

    const float* XA = sAX + eA * 68;
    const float* XB = sAX + eB * 68;
    vf4 shA = *(const vf4*)(XA + 56);
    vf4 shB = *(const vf4*)(XB + 56);

    const unsigned short* Ab = g_w2t + le * EF + g * 8;
    const float* B2 = fc_b2 + g * 4;

    float o0aA[8] = {0,0,0,0,0,0,0,0}, o0aB[8] = {0,0,0,0,0,0,0,0};
    float o0bA[8] = {0,0,0,0,0,0,0,0}, o0bB[8] = {0,0,0,0,0,0,0,0};
    float o1A[4][3] = {{0,0,0},{0,0,0},{0,0,0},{0,0,0}};
    float o1B[4][3] = {{0,0,0},{0,0,0},{0,0,0},{0,0,0}};

    // w1: tiles 0..63
    #pragma unroll 2
    for (int t2 = 0; t2 < 32; ++t2) {
        const unsigned short* At = Ab + t2 * 2048;
        bfrag a00 = *(const bfrag*)(At);
        bfrag a01 = *(const bfrag*)(At + 32);
        bfrag a10 = *(const bfrag*)(At + 1024);
        bfrag a11 = *(const bfrag*)(At + 1056);
        vf4 b20 = *(const vf4*)(B2 + t2 * 32);
        vf4 b21 = *(const vf4*)(B2 + t2 * 32 + 16);
        float xuA = XA[t2], xuB = XB[t2];
        vf4 dA0 = mm2(a00, a01, bA0, bA1);
        vf4 dB0 = mm2(a00, a01, bB0, bB1);
        vf4 dA1 = mm2(a10, a11, bA0, bA1);
        vf4 dB1 = mm2(a10, a11, bB0, bB1);
        #pragma unroll
        for (int r = 0; r < 4; ++r) {
            o0aA[r]     = fmaf(xuA, dA0[r] + b20[r], o0aA[r]);
            o0aB[r]     = fmaf(xuB, dB0[r] + b20[r], o0aB[r]);
            o0aA[4 + r] = fmaf(xuA, dA1[r] + b21[r], o0aA[4 + r]);
            o0aB[4 + r] = fmaf(xuB, dB1[r] + b21[r], o0aB[4 + r]);
        }
    }

    // w2: tiles 64..79
    #pragma unroll 2
    for (int t = 64; t < 80; ++t) {
        const unsigned short* At = Ab + t * 1024;
        bfrag a0 = *(const bfrag*)(At);
        bfrag a1 = *(const bfrag*)(At + 32);
        vf4 b2v = *(const vf4*)(B2 + t * 16);
        int u = 2 * (t - 64) + (g >> 1);
        float xuA = XA[u], xuB = XB[u];
        float cA0 = xuA * shA[1], cA1 = xuA * shA[2], cA2 = xuA * shA[3];
        float cB0 = xuB * shB[1], cB1 = xuB * shB[2], cB2 = xuB * shB[3];
        vf4 dA = mm2(a0, a1, bA0, bA1);
        vf4 dB = mm2(a0, a1, bB0, bB1);
        #pragma unroll
        for (int r = 0; r < 4; ++r) {
            float WA = dA[r] + b2v[r], WB = dB[r] + b2v[r];
            o1A[r][0] = fmaf(cA0, WA, o1A[r][0]);
            o1A[r][1] = fmaf(cA1, WA, o1A[r][1]);
            o1A[r][2] = fmaf(cA2, WA, o1A[r][2]);
            o1B[r][0] = fmaf(cB0, WB, o1B[r][0]);
            o1B[r][1] = fmaf(cB1, WB, o1B[r][1]);
            o1B[r][2] = fmaf(cB2, WB, o1B[r][2]);
        }
    }

    // w3: tiles 80..83
    #pragma unroll
    for (int t = 80; t < 84; ++t) {
        const unsigned short* At = Ab + t * 1024;
        bfrag a0 = *(const bfrag*)(At);
        bfrag a1 = *(const bfrag*)(At + 32);
        vf4 b2v = *(const vf4*)(B2 + t * 16);
        int u = 2 * (t - 80) + (g >> 1);
        float cA0 = shA[0] * XA[32 + u * 3 + 0];
        float cA1 = shA[0] * XA[32 + u * 3 + 1];
        float cA2 = shA[0] * XA[32 + u * 3 + 2];
        float cB0 = shB[0] * XB[32 + u * 3 + 0];
        float cB1 = shB[0] * XB[32 + u * 3 + 1];
        float cB2 = shB[0] * XB[32 + u * 3 + 2];
        vf4 dA = mm2(a0, a1, bA0, bA1);
        vf4 dB = mm2(a0, a1, bB0, bB1);
        #pragma unroll
        for (int r = 0; r < 4; ++r) {
            float WA = dA[r] + b2v[r], WB = dB[r] + b2v[r];
            o1A[r][0] = fmaf(cA0, WA, o1A[r][0]);
            o1A[r][1] = fmaf(cA1, WA, o1A[r][1]);
            o1A[r][2] = fmaf(cA2, WA, o1A[r][2]);
            o1B[r][0] = fmaf(cB0, WB, o1B[r][0]);
            o1B[r][1] = fmaf(cB1, WB, o1B[r][1]);
            o1B[r][2] = fmaf(cB2, WB, o1B[r][2]);
        }
    }

    // w4: tiles 84..99
    #pragma unroll 2
    for (int t2 = 0; t2 < 8; ++t2) {
        const unsigned short* At = Ab + (84 + 2 * t2) * 1024;
        bfrag a00 = *(const bfrag*)(At);
        bfrag a01 = *(const bfrag*)(At + 32);
        bfrag a10 = *(const bfrag*)(At + 1024);
        bfrag a11 = *(const bfrag*)(At + 1056);
        vf4 b20 = *(const vf4*)(B2 + (84 + 2 * t2) * 16);
        vf4 b21 = *(const vf4*)(B2 + (84 + 2 * t2) * 16 + 16);
        float dqA = XA[60 + t2], dqB = XB[60 + t2];
        vf4 dA0 = mm2(a00, a01, bA0, bA1);
        vf4 dB0 = mm2(a00, a01, bB0, bB1);
        vf4 dA1 = mm2(a10, a11, bA0, bA1);
        vf4 dB1 = mm2(a10, a11, bB0, bB1);
        #pragma unroll
        for (int r = 0; r < 4; ++r) {
            o0bA[r]     = fmaf(dqA, dA0[r] + b20[r], o0bA[r]);
            o0bB[r]     = fmaf(dqB, dB0[r] + b20[r], o0bB[r]);
            o0bA[4 + r] = fmaf(dqA, dA1[r] + b21[r], o0bA[4 + r]);
            o0bB[4 + r] = fmaf(dqB, dB1[r] + b21[r], o0bB[4 + r]);
        }
    }

    // ---- aggregation: per-edge rows to LDS, serial per-head segment sums ----
    __syncthreads();                              // all waves done reading sAX/sHb
    float* sTP = sm;                              // [128][60], overlays sAX
    #pragma unroll
    for (int j = 0; j < 8; ++j) {
        int w = (j >> 2) * 16 + g * 4 + (j & 3);
        sTP[eA * 60 + w] = (shA[0] * o0aA[j] + ISQ3 * o0bA[j]) * ALPHA;
        sTP[eB * 60 + w] = (shB[0] * o0aB[j] + ISQ3 * o0bB[j]) * ALPHA;
    }
    #pragma unroll
    for (int r = 0; r < 4; ++r)
        #pragma unroll
        for (int j = 0; j < 3; ++j) {
            o1A[r][j] += __shfl_xor(o1A[r][j], 32);
            o1B[r][j] += __shfl_xor(o1B[r][j], 32);
        }
    if (lane < 32) {
        #pragma unroll
        for (int r = 0; r < 4; ++r) {
            int wp = g * 4 + r;                   // g in {0,1}
            #pragma unroll
            for (int j = 0; j < 3; ++j) {
                sTP[eA * 60 + 32 + wp * 3 + j] = o1A[r][j] * ALPHA;
                sTP[eB * 60 + 32 + wp * 3 + j] = o1B[r][j] * ALPHA;
            }
        }
    }
    int* sSrc  = (int*)(sm + 8704);               // [128]
    int* sIsHd = sSrc + 128;                      // [128]
    int* sEnd  = sIsHd + 128;                     // [128]
    if (tid < 128) sSrc[tid] = edge_index[perm[e0 + tid]];
    __syncthreads();                              // sTP + sSrc visible
    if (tid < 128) {
        int head = (tid == 0 || sSrc[tid] != sSrc[tid - 1]) ? 1 : 0;
        sIsHd[tid] = head;
        if (head) {
            int e = tid + 1, n = sSrc[tid];
            while (e < 128 && sSrc[e] == n) ++e;
            sEnd[tid] = e;
        }
    }
    __syncthreads();
    for (int k = 0; k < 28; ++k) {                // 7168 = 128*56 items
        int item = k * 256 + tid;
        int i = item / 56, w = item - i * 56;
        if (sIsHd[i]) {
            float v = 0.f;
            int end = sEnd[i];
            for (int r = i; r < end; ++r) v += sTP[r * 60 + w];
            atomicAdd(seg + (size_t)sSrc[i] * ND + w, v);
        }
    }
}

__global__ __launch_bounds__(256)
void tp_finalize(const float* __restrict__ node_attr,
                 const int* __restrict__ cnt,
                 float* __restrict__ out, int totalf4)
{
    int idx = blockIdx.x * 256 + threadIdx.x;
    if (idx >= totalf4) return;
    int n = idx / 14;
    float inv = 1.f / fmaxf((float)cnt[n], 1.f);
    float4 s = *(float4*)(out + (size_t)idx * 4);
    const float4 a = *(const float4*)(node_attr + (size_t)idx * 4);
    s.x = fmaf(s.x, inv, a.x);
    s.y = fmaf(s.y, inv, a.y);
    s.z = fmaf(s.z, inv, a.z);
    s.w = fmaf(s.w, inv, a.w);
    *(float4*)(out + (size_t)idx * 4) = s;
}

extern "C" void kernel_launch(void* const* d_in, const int* in_sizes, int n_in,
                              void* d_out, int out_size, void* d_ws, size_t ws_size,
                              hipStream_t stream)
{
    const float* node_attr  = (const float*)d_in[0];
    const int*   edge_index = (const int*)d_in[1];
    const float* edge_attr  = (const float*)d_in[2];
    const float* edge_sh    = (const float*)d_in[3];
    const float* fc_w1      = (const float*)d_in[4];
    const float* fc_b1      = (const float*)d_in[5];
    const float* fc_w2      = (const float*)d_in[6];
    const float* fc_b2      = (const float*)d_in[7];
    float* seg = (float*)d_out;

    // ws layout (ints), total 500512 ints = 2.0 MB
    int* ws     = (int*)d_ws;
    int* hist   = ws;                      // 50000
    int* cursor = ws + 50000;              // 50000
    int* bsum   = ws + 100000;             // 256
    int* bbase  = ws + 100256;             // 256
    int* perm   = ws + 100512;             // 400000

    hipMemsetAsync(hist, 0, N_NODES * sizeof(int), stream);
    hipMemsetAsync(d_out, 0, (size_t)out_size * sizeof(float), stream);

    k_hist<<<(N_EDGES + 255) / 256, 256, 0, stream>>>(edge_index, hist);
    k_scan1<<<NB_SCAN, 256, 0, stream>>>(hist, bsum);
    k_scan2<<<1, 256, 0, stream>>>(bsum, bbase);
    k_scan3<<<NB_SCAN, 256, 0, stream>>>(hist, bbase, cursor);
    k_scatter<<<(N_EDGES + 255) / 256, 256, 0, stream>>>(edge_index, cursor, perm);

    w2t_conv<<<EF, 256, 0, stream>>>(fc_w2);

    tp_fused<<<N_EDGES / EB, 256, 0, stream>>>(
        node_attr, edge_index, edge_attr, edge_sh,
        fc_w1, fc_b1, fc_b2, seg, perm);

    int totalf4 = N_NODES * (ND / 4);
    tp_finalize<<<(totalf4 + 255) / 256, 256, 0, stream>>>(node_attr, hist, seg, totalf4);
}